// Round 7
// baseline (130.835 us; speedup 1.0000x reference)
//
#include <hip/hip_runtime.h>

// EdgeTypeGNNLayer on MI355X — atomic-append bucketing + fused accum+MFMA,
// bf16 X gather (L2-resident).
//
//   row(n) = [ sum_{e:type0,dst=n} Xb[src] | sum_{e:type1} Xb[src] | Xb[n] ]
//   out    = relu(row @ [Wd|Wc|Ws].T + c0*bd + c1*bc + bs)        fp32
//
// R6 accounting: fixed harness overhead ~95-100 us (268 MB ws-poison fill at
// ~42 us + restores + out fill); our pipeline ~30 us (prep 3, append 10,
// fused 15). R7: instruction diet in the gather loop (sum_all + sum_t1
// instead of two masked sets), 2-edge/thread append. Near the floor:
// append bounded by 640k atomics @74 G/s (8.6 us), fused by L2 gather BW
// (164 MB @34.5 TB/s = 4.8 us) + ~4.5 us VALU.

#define IN_DIM 128
#define K_CAT  384
#define CAP    256     // bucket capacity; degree ~ Poisson(64), P(>256) ~ 0
#define CSTR   16      // bucket counter stride in ints: one per 64B line
#define ROWP   392     // padded LDS row length in shorts (384+8)

typedef short short8  __attribute__((ext_vector_type(8)));
typedef float floatx4 __attribute__((ext_vector_type(4)));

#define NW_ITEMS (8 * 12 * 64)      // WB short8 items

__device__ inline unsigned short f2bf(float f) {
    unsigned u = __float_as_uint(f);
    u += 0x7FFF + ((u >> 16) & 1);          // RNE
    return (unsigned short)(u >> 16);
}
__device__ inline float bu2f(unsigned short h) {
    return __uint_as_float(((unsigned)h) << 16);
}

// One kernel, three independent jobs (flat virtual index):
//  [0, NW)            : build WB in MFMA B-fragment order
//  [NW, NW+NX)        : convert X fp32 -> bf16 (float4 -> ushort4)
//  [NW+NX, NW+NX+NC)  : zero cnt (int4)
__global__ __launch_bounds__(256) void prep_kernel(
    const float* __restrict__ X,
    const float* __restrict__ Wd, const float* __restrict__ Wc,
    const float* __restrict__ Ws,
    unsigned short* __restrict__ WB,
    unsigned short* __restrict__ Xb,
    int* __restrict__ cnt, int N)
{
    const int NX = N * 32;          // float4 items of X
    const int NC = N * CSTR / 4;    // int4 items of cnt
    int idx = blockIdx.x * 256 + threadIdx.x;

    if (idx < NW_ITEMS) {
        // WB[(nt*12 + kt)*64 + lane]: lane's short8 for n-tile nt, k-step kt
        //   col = nt*16 + (lane&15), k = kt*32 + (lane>>4)*8 + j
        int lane = idx & 63;
        int kt   = (idx >> 6) % 12;
        int nt   = idx / (64 * 12);
        int col  = nt * 16 + (lane & 15);
        int kb   = kt * 32 + (lane >> 4) * 8;
        unsigned short v[8];
        #pragma unroll
        for (int j = 0; j < 8; j++) {
            int k = kb + j;
            float w = (k < 128) ? Wd[col * 128 + k]
                    : (k < 256) ? Wc[col * 128 + (k - 128)]
                                : Ws[col * 128 + (k - 256)];
            v[j] = f2bf(w);
        }
        *(short8*)(WB + (size_t)idx * 8) = *(short8*)v;
        return;
    }
    idx -= NW_ITEMS;
    if (idx < NX) {
        float4 v = ((const float4*)X)[idx];
        ushort4 o;
        o.x = f2bf(v.x); o.y = f2bf(v.y); o.z = f2bf(v.z); o.w = f2bf(v.w);
        ((ushort4*)Xb)[idx] = o;
        return;
    }
    idx -= NX;
    if (idx < NC) {
        ((int4*)cnt)[idx] = make_int4(0, 0, 0, 0);
    }
}

// 2 edges per thread (int2 loads on src/dst/etype).
__global__ __launch_bounds__(256) void append_kernel(
    const int* __restrict__ src,
    const int* __restrict__ dst,
    const int* __restrict__ etype,
    int* __restrict__ cnt,
    unsigned short* __restrict__ bucket, int E)
{
    int e = (blockIdx.x * 256 + threadIdx.x) * 2;
    if (e + 1 < E) {
        int2 s = *(const int2*)(src + e);
        int2 d = *(const int2*)(dst + e);
        int2 t = *(const int2*)(etype + e);
        int p0 = atomicAdd(&cnt[d.x * CSTR], 1);
        if (p0 < CAP)
            bucket[(size_t)d.x * CAP + p0] = (unsigned short)(s.x | (t.x << 15));
        int p1 = atomicAdd(&cnt[d.y * CSTR], 1);
        if (p1 < CAP)
            bucket[(size_t)d.y * CAP + p1] = (unsigned short)(s.y | (t.y << 15));
    } else if (e < E) {
        int p = atomicAdd(&cnt[dst[e] * CSTR], 1);
        if (p < CAP)
            bucket[(size_t)dst[e] * CAP + p] =
                (unsigned short)(src[e] | (etype[e] << 15));
    }
}

// Block = 512 threads = 16 half-waves = 16 nodes (one 16-row MFMA M-tile).
// Phase 1: half-wave hw gathers bf16 X rows (8 B/lane/edge, L2-resident),
//          accumulates sum_all + sum_type1 in fp32 (a0 = all - a1 at the
//          end), writes LDS row (bf16).
// Phase 2: 8 waves, wave w = n-tile w, K=384 in 12 MFMA steps; A from LDS
//          (ds_read_b128), B coalesced from fragment-ordered WB.
// Frag layouts (m89/m120-verified):
//   A: lane holds A[m=lane&15][kt*32 + (lane>>4)*8 ..+7]
//   B: lane holds B[k][n=lane&15]
//   D: lane reg r -> C[row=(lane>>4)*4 + r][col=lane&15]
__global__ __launch_bounds__(512) void fused_kernel(
    const unsigned short* __restrict__ Xb,
    const int* __restrict__ cnt,
    const unsigned short* __restrict__ bucket,
    const unsigned short* __restrict__ WB,
    const float* __restrict__ bd, const float* __restrict__ bc,
    const float* __restrict__ bs,
    float* __restrict__ out, int N)
{
    __shared__ unsigned short Als[16][ROWP];   // 12.25 KB, rows 16B-aligned
    __shared__ float lc0[16], lc1[16];

    const int tid = threadIdx.x;
    const int m0  = blockIdx.x * 16;

    // ---------- phase 1: accumulate ----------
    {
        const int hw = tid >> 5;
        const int q  = tid & 31;
        const int d  = m0 + hw;
        if (d < N) {
            const ushort4* Xb4 = (const ushort4*)Xb;   // row = 32 ushort4
            int len = cnt[d * CSTR];
            if (len > CAP) len = CAP;

            float4 aA = make_float4(0.f, 0.f, 0.f, 0.f);   // sum over all
            float4 a1 = make_float4(0.f, 0.f, 0.f, 0.f);   // sum over type1
            int n1 = 0;
            const unsigned short* bl = bucket + (size_t)d * CAP;

#define PROC(P) do {                                                     \
            int _p = (int)(P);                                           \
            int _s = _p & 0x7FFF;                                        \
            int _t = _p >> 15;                                           \
            ushort4 _u = Xb4[_s * 32 + q];                               \
            float _x = bu2f(_u.x), _y = bu2f(_u.y);                      \
            float _z = bu2f(_u.z), _w = bu2f(_u.w);                      \
            float _m1 = (float)_t;                                       \
            aA.x += _x; aA.y += _y; aA.z += _z; aA.w += _w;              \
            a1.x = fmaf(_x, _m1, a1.x); a1.y = fmaf(_y, _m1, a1.y);      \
            a1.z = fmaf(_z, _m1, a1.z); a1.w = fmaf(_w, _m1, a1.w);      \
            n1 += _t;                                                    \
        } while (0)
#define PROC8(PP) do {                                                   \
            PROC((PP).x & 0xFFFF); PROC((PP).x >> 16);                   \
            PROC((PP).y & 0xFFFF); PROC((PP).y >> 16);                   \
            PROC((PP).z & 0xFFFF); PROC((PP).z >> 16);                   \
            PROC((PP).w & 0xFFFF); PROC((PP).w >> 16);                   \
        } while (0)

            int i = 0;
            for (; i + 16 <= len; i += 16) {       // 16 gathers in flight
                uint4 p0 = *(const uint4*)(bl + i);
                uint4 p1 = *(const uint4*)(bl + i + 8);
                PROC8(p0); PROC8(p1);
            }
            for (; i + 8 <= len; i += 8) {
                uint4 p0 = *(const uint4*)(bl + i);
                PROC8(p0);
            }
            for (; i < len; i++) PROC(bl[i]);
#undef PROC8
#undef PROC

            // a0 = all - type1
            float4 a0;
            a0.x = aA.x - a1.x; a0.y = aA.y - a1.y;
            a0.z = aA.z - a1.z; a0.w = aA.w - a1.w;

            ushort4 ux = Xb4[d * 32 + q];          // self row, already bf16
            unsigned short* row = &Als[hw][0];
            ushort4 o;
            o.x = f2bf(a0.x); o.y = f2bf(a0.y); o.z = f2bf(a0.z); o.w = f2bf(a0.w);
            *(ushort4*)(row + q * 4) = o;
            o.x = f2bf(a1.x); o.y = f2bf(a1.y); o.z = f2bf(a1.z); o.w = f2bf(a1.w);
            *(ushort4*)(row + 128 + q * 4) = o;
            *(ushort4*)(row + 256 + q * 4) = ux;
            if (q == 0) {
                lc0[hw] = (float)(len - n1);
                lc1[hw] = (float)n1;
            }
        }
    }
    __syncthreads();

    // ---------- phase 2: MFMA gemm ----------
    const int wave = tid >> 6;          // n-tile (0..7)
    const int lane = tid & 63;
    const int rA   = lane & 15;
    const int quad = lane >> 4;

    floatx4 acc = (floatx4){0.f, 0.f, 0.f, 0.f};
    const short8* B8 = (const short8*)WB + (size_t)wave * 12 * 64 + lane;

    #pragma unroll
    for (int kt = 0; kt < 12; kt++) {
        short8 a = *(const short8*)&Als[rA][kt * 32 + quad * 8];
        short8 b = B8[kt * 64];
        acc = __builtin_amdgcn_mfma_f32_16x16x32_bf16(a, b, acc, 0, 0, 0);
    }

    const int col = wave * 16 + rA;
    const float bdv = bd[col], bcv = bc[col], bsv = bs[col];
    #pragma unroll
    for (int r = 0; r < 4; r++) {
        int lrow = quad * 4 + r;
        int grow = m0 + lrow;
        if (grow < N) {
            float v = acc[r] + lc0[lrow] * bdv + lc1[lrow] * bcv + bsv;
            out[(size_t)grow * 128 + col] = fmaxf(v, 0.f);
        }
    }
}

extern "C" void kernel_launch(void* const* d_in, const int* in_sizes, int n_in,
                              void* d_out, int out_size, void* d_ws, size_t ws_size,
                              hipStream_t stream) {
    const float* X  = (const float*)d_in[0];
    const int*   ei = (const int*)d_in[1];    // [src(E) | dst(E)]
    const int*   et = (const int*)d_in[2];
    const float* Wd = (const float*)d_in[3];
    const float* bd = (const float*)d_in[4];
    const float* Wc = (const float*)d_in[5];
    const float* bc = (const float*)d_in[6];
    const float* Ws = (const float*)d_in[7];
    const float* bs = (const float*)d_in[8];
    float* out = (float*)d_out;

    const int N = in_sizes[0] / IN_DIM;       // 10000
    const int E = in_sizes[2];                // 640000

    // workspace layout (16B-aligned sections)
    unsigned short* WB     = (unsigned short*)d_ws;            // 8*12*64*8 bf16
    unsigned short* Xb     = WB + (size_t)NW_ITEMS * 8;        // N*128 bf16
    unsigned short* bucket = Xb + (size_t)N * IN_DIM;          // N*CAP ushort
    int*            cnt    = (int*)(bucket + (size_t)N * CAP); // N*CSTR ints

    const int* src = ei;
    const int* dst = ei + E;

    int prep_items = NW_ITEMS + N * 32 + N * CSTR / 4;
    prep_kernel<<<(prep_items + 255) / 256, 256, 0, stream>>>(
        X, Wd, Wc, Ws, WB, Xb, cnt, N);

    int eb = (E / 2 + 255) / 256;
    append_kernel<<<eb, 256, 0, stream>>>(src, dst, et, cnt, bucket, E);

    int fb = (N + 15) / 16;
    fused_kernel<<<fb, 512, 0, stream>>>(Xb, cnt, bucket, WB, bd, bc, bs, out, N);
}

// Round 8
// 130.345 us; speedup vs baseline: 1.0038x; 1.0038x over previous
//
#include <hip/hip_runtime.h>

// EdgeTypeGNNLayer on MI355X — atomic-append bucketing + fused accum+MFMA,
// with bf16 X gather (L2-resident). [R8 = revert to R6 best-known config]
//
//   row(n) = [ sum_{e:type0,dst=n} Xb[src] | sum_{e:type1} Xb[src] | Xb[n] ]
//   out    = relu(row @ [Wd|Wc|Ws].T + c0*bd + c1*bc + bs)        fp32
//
// R7 lesson: 2-edge/thread append (serialized dependent atomics) regressed
// ~2 us — atomic throughput needs issue parallelism, 1 edge/thread is right.
// Phase-1 is gather-bound, not VALU-bound: instruction diets don't show.
// Accounting: ~100 us fixed harness overhead (268 MB ws-poison fill ~42 us
// + restores); our pipeline ~30 us (prep ~3, append ~10 = 640k atomics at
// 74 G/s floor, fused ~15 = L2 gather BW floor + latency).

#define IN_DIM 128
#define K_CAT  384
#define CAP    256     // bucket capacity; degree ~ Poisson(64), P(>256) ~ 0
#define CSTR   16      // bucket counter stride in ints: one per 64B line
#define ROWP   392     // padded LDS row length in shorts (384+8)

typedef short short8  __attribute__((ext_vector_type(8)));
typedef float floatx4 __attribute__((ext_vector_type(4)));

#define NW_ITEMS (8 * 12 * 64)      // WB short8 items

__device__ inline unsigned short f2bf(float f) {
    unsigned u = __float_as_uint(f);
    u += 0x7FFF + ((u >> 16) & 1);          // RNE
    return (unsigned short)(u >> 16);
}
__device__ inline float bu2f(unsigned short h) {
    return __uint_as_float(((unsigned)h) << 16);
}

// One kernel, three independent jobs (flat virtual index):
//  [0, NW)            : build WB in MFMA B-fragment order
//  [NW, NW+NX)        : convert X fp32 -> bf16 (float4 -> ushort4)
//  [NW+NX, NW+NX+NC)  : zero cnt (int4)
__global__ __launch_bounds__(256) void prep_kernel(
    const float* __restrict__ X,
    const float* __restrict__ Wd, const float* __restrict__ Wc,
    const float* __restrict__ Ws,
    unsigned short* __restrict__ WB,
    unsigned short* __restrict__ Xb,
    int* __restrict__ cnt, int N)
{
    const int NX = N * 32;          // float4 items of X
    const int NC = N * CSTR / 4;    // int4 items of cnt
    int idx = blockIdx.x * 256 + threadIdx.x;

    if (idx < NW_ITEMS) {
        // WB[(nt*12 + kt)*64 + lane]: lane's short8 for n-tile nt, k-step kt
        //   col = nt*16 + (lane&15), k = kt*32 + (lane>>4)*8 + j
        int lane = idx & 63;
        int kt   = (idx >> 6) % 12;
        int nt   = idx / (64 * 12);
        int col  = nt * 16 + (lane & 15);
        int kb   = kt * 32 + (lane >> 4) * 8;
        unsigned short v[8];
        #pragma unroll
        for (int j = 0; j < 8; j++) {
            int k = kb + j;
            float w = (k < 128) ? Wd[col * 128 + k]
                    : (k < 256) ? Wc[col * 128 + (k - 128)]
                                : Ws[col * 128 + (k - 256)];
            v[j] = f2bf(w);
        }
        *(short8*)(WB + (size_t)idx * 8) = *(short8*)v;
        return;
    }
    idx -= NW_ITEMS;
    if (idx < NX) {
        float4 v = ((const float4*)X)[idx];
        ushort4 o;
        o.x = f2bf(v.x); o.y = f2bf(v.y); o.z = f2bf(v.z); o.w = f2bf(v.w);
        ((ushort4*)Xb)[idx] = o;
        return;
    }
    idx -= NX;
    if (idx < NC) {
        ((int4*)cnt)[idx] = make_int4(0, 0, 0, 0);
    }
}

// 1 edge/thread: max atomic-issue parallelism (R7's 2-edge variant regressed).
__global__ __launch_bounds__(256) void append_kernel(
    const int* __restrict__ src,
    const int* __restrict__ dst,
    const int* __restrict__ etype,
    int* __restrict__ cnt,
    unsigned short* __restrict__ bucket, int E)
{
    int e = blockIdx.x * 256 + threadIdx.x;
    if (e >= E) return;
    int d = dst[e];
    int pos = atomicAdd(&cnt[d * CSTR], 1);
    if (pos < CAP) {
        bucket[(size_t)d * CAP + pos] =
            (unsigned short)(src[e] | (etype[e] << 15));
    }
}

// Block = 512 threads = 16 half-waves = 16 nodes (one 16-row MFMA M-tile).
// Phase 1: half-wave hw gathers bf16 X rows (8 B/lane/edge, L2-resident),
//          accumulates type0/type1 sums in fp32, writes LDS row (bf16).
// Phase 2: 8 waves, wave w = n-tile w, K=384 in 12 MFMA steps; A from LDS
//          (ds_read_b128), B coalesced from fragment-ordered WB.
// Frag layouts (m89/m120-verified):
//   A: lane holds A[m=lane&15][kt*32 + (lane>>4)*8 ..+7]
//   B: lane holds B[k][n=lane&15]
//   D: lane reg r -> C[row=(lane>>4)*4 + r][col=lane&15]
__global__ __launch_bounds__(512) void fused_kernel(
    const unsigned short* __restrict__ Xb,
    const int* __restrict__ cnt,
    const unsigned short* __restrict__ bucket,
    const unsigned short* __restrict__ WB,
    const float* __restrict__ bd, const float* __restrict__ bc,
    const float* __restrict__ bs,
    float* __restrict__ out, int N)
{
    __shared__ unsigned short Als[16][ROWP];   // 12.25 KB, rows 16B-aligned
    __shared__ float lc0[16], lc1[16];

    const int tid = threadIdx.x;
    const int m0  = blockIdx.x * 16;

    // ---------- phase 1: accumulate ----------
    {
        const int hw = tid >> 5;
        const int q  = tid & 31;
        const int d  = m0 + hw;
        if (d < N) {
            const ushort4* Xb4 = (const ushort4*)Xb;   // row = 32 ushort4
            int len = cnt[d * CSTR];
            if (len > CAP) len = CAP;

            float4 a0 = make_float4(0.f, 0.f, 0.f, 0.f);
            float4 a1 = make_float4(0.f, 0.f, 0.f, 0.f);
            int n0 = 0;
            const unsigned short* bl = bucket + (size_t)d * CAP;

#define PROC(P) do {                                                     \
            int _p = (int)(P);                                           \
            int _s = _p & 0x7FFF;                                        \
            int _t = _p >> 15;                                           \
            ushort4 _u = Xb4[_s * 32 + q];                               \
            float _x = bu2f(_u.x), _y = bu2f(_u.y);                      \
            float _z = bu2f(_u.z), _w = bu2f(_u.w);                      \
            float _m0 = _t ? 0.f : 1.f;                                  \
            float _m1 = 1.f - _m0;                                       \
            a0.x = fmaf(_x, _m0, a0.x); a1.x = fmaf(_x, _m1, a1.x);      \
            a0.y = fmaf(_y, _m0, a0.y); a1.y = fmaf(_y, _m1, a1.y);      \
            a0.z = fmaf(_z, _m0, a0.z); a1.z = fmaf(_z, _m1, a1.z);      \
            a0.w = fmaf(_w, _m0, a0.w); a1.w = fmaf(_w, _m1, a1.w);      \
            n0 += 1 - _t;                                                \
        } while (0)
#define PROC8(PP) do {                                                   \
            PROC((PP).x & 0xFFFF); PROC((PP).x >> 16);                   \
            PROC((PP).y & 0xFFFF); PROC((PP).y >> 16);                   \
            PROC((PP).z & 0xFFFF); PROC((PP).z >> 16);                   \
            PROC((PP).w & 0xFFFF); PROC((PP).w >> 16);                   \
        } while (0)

            int i = 0;
            for (; i + 16 <= len; i += 16) {       // 16 gathers in flight
                uint4 p0 = *(const uint4*)(bl + i);
                uint4 p1 = *(const uint4*)(bl + i + 8);
                PROC8(p0); PROC8(p1);
            }
            for (; i + 8 <= len; i += 8) {
                uint4 p0 = *(const uint4*)(bl + i);
                PROC8(p0);
            }
            for (; i < len; i++) PROC(bl[i]);
#undef PROC8
#undef PROC

            ushort4 ux = Xb4[d * 32 + q];          // self row, already bf16
            unsigned short* row = &Als[hw][0];
            ushort4 o;
            o.x = f2bf(a0.x); o.y = f2bf(a0.y); o.z = f2bf(a0.z); o.w = f2bf(a0.w);
            *(ushort4*)(row + q * 4) = o;
            o.x = f2bf(a1.x); o.y = f2bf(a1.y); o.z = f2bf(a1.z); o.w = f2bf(a1.w);
            *(ushort4*)(row + 128 + q * 4) = o;
            *(ushort4*)(row + 256 + q * 4) = ux;
            if (q == 0) {
                lc0[hw] = (float)n0;
                lc1[hw] = (float)(len - n0);
            }
        }
    }
    __syncthreads();

    // ---------- phase 2: MFMA gemm ----------
    const int wave = tid >> 6;          // n-tile (0..7)
    const int lane = tid & 63;
    const int rA   = lane & 15;
    const int quad = lane >> 4;

    floatx4 acc = (floatx4){0.f, 0.f, 0.f, 0.f};
    const short8* B8 = (const short8*)WB + (size_t)wave * 12 * 64 + lane;

    #pragma unroll
    for (int kt = 0; kt < 12; kt++) {
        short8 a = *(const short8*)&Als[rA][kt * 32 + quad * 8];
        short8 b = B8[kt * 64];
        acc = __builtin_amdgcn_mfma_f32_16x16x32_bf16(a, b, acc, 0, 0, 0);
    }

    const int col = wave * 16 + rA;
    const float bdv = bd[col], bcv = bc[col], bsv = bs[col];
    #pragma unroll
    for (int r = 0; r < 4; r++) {
        int lrow = quad * 4 + r;
        int grow = m0 + lrow;
        if (grow < N) {
            float v = acc[r] + lc0[lrow] * bdv + lc1[lrow] * bcv + bsv;
            out[(size_t)grow * 128 + col] = fmaxf(v, 0.f);
        }
    }
}

extern "C" void kernel_launch(void* const* d_in, const int* in_sizes, int n_in,
                              void* d_out, int out_size, void* d_ws, size_t ws_size,
                              hipStream_t stream) {
    const float* X  = (const float*)d_in[0];
    const int*   ei = (const int*)d_in[1];    // [src(E) | dst(E)]
    const int*   et = (const int*)d_in[2];
    const float* Wd = (const float*)d_in[3];
    const float* bd = (const float*)d_in[4];
    const float* Wc = (const float*)d_in[5];
    const float* bc = (const float*)d_in[6];
    const float* Ws = (const float*)d_in[7];
    const float* bs = (const float*)d_in[8];
    float* out = (float*)d_out;

    const int N = in_sizes[0] / IN_DIM;       // 10000
    const int E = in_sizes[2];                // 640000

    // workspace layout (16B-aligned sections)
    unsigned short* WB     = (unsigned short*)d_ws;            // 8*12*64*8 bf16
    unsigned short* Xb     = WB + (size_t)NW_ITEMS * 8;        // N*128 bf16
    unsigned short* bucket = Xb + (size_t)N * IN_DIM;          // N*CAP ushort
    int*            cnt    = (int*)(bucket + (size_t)N * CAP); // N*CSTR ints

    const int* src = ei;
    const int* dst = ei + E;

    int prep_items = NW_ITEMS + N * 32 + N * CSTR / 4;
    prep_kernel<<<(prep_items + 255) / 256, 256, 0, stream>>>(
        X, Wd, Wc, Ws, WB, Xb, cnt, N);

    int eb = (E + 255) / 256;
    append_kernel<<<eb, 256, 0, stream>>>(src, dst, et, cnt, bucket, E);

    int fb = (N + 15) / 16;
    fused_kernel<<<fb, 512, 0, stream>>>(Xb, cnt, bucket, WB, bd, bc, bs, out, N);
}